// Round 5
// baseline (600.023 us; speedup 1.0000x reference)
//
#include <hip/hip_runtime.h>

typedef unsigned short u16;
typedef unsigned int   u32;
typedef __attribute__((ext_vector_type(8))) __bf16 bf16x8;
typedef __attribute__((ext_vector_type(4))) float  f32x4;

#define HW 4096
#define NPOS 65536
#define CH 256
#define MT 512   // number of 128-row M tiles

__device__ __forceinline__ u16 f2bf(float f){
  u32 u = __float_as_uint(f);
  u += 0x7FFFu + ((u >> 16) & 1u);
  return (u16)(u >> 16);
}
__device__ __forceinline__ float bflo(u32 p){ return __uint_as_float(p << 16); }
__device__ __forceinline__ float bfhi(u32 p){ return __uint_as_float(p & 0xFFFF0000u); }

// ---------------- x plane stats: total, edge rows/cols, corners ----------------
__global__ __launch_bounds__(256) void k_statsx(const float* __restrict__ x, float* __restrict__ stats){
  int bc = blockIdx.x; int tid = threadIdx.x;
  const float* xp = x + (size_t)bc * HW;
  float S=0.f, r0=0.f, r1=0.f, c0=0.f, c1=0.f;
  #pragma unroll
  for (int k=0;k<4;k++){
    int i4 = tid + k*256;
    float4 v = ((const float4*)xp)[i4];
    int pos = i4*4; int h = pos>>6; int wb = pos&63;
    float sv = v.x+v.y+v.z+v.w;
    S += sv;
    if (h==0)  r0 += sv;
    if (h==63) r1 += sv;
    if (wb==0)  c0 += v.x;
    if (wb==60) c1 += v.w;
  }
  __shared__ float red[4][5];
  #pragma unroll
  for (int off=32; off>0; off>>=1){
    S  += __shfl_down(S, off);
    r0 += __shfl_down(r0, off);
    r1 += __shfl_down(r1, off);
    c0 += __shfl_down(c0, off);
    c1 += __shfl_down(c1, off);
  }
  if ((tid & 63) == 0){
    int w = tid >> 6;
    red[w][0]=S; red[w][1]=r0; red[w][2]=r1; red[w][3]=c0; red[w][4]=c1;
  }
  __syncthreads();
  if (tid == 0){
    float* o = stats + (size_t)bc * 9;
    for (int j=0;j<5;j++) o[j] = red[0][j]+red[1][j]+red[2][j]+red[3][j];
    o[5] = xp[0];    // x[0][0]
    o[6] = xp[63];   // x[0][63]
    o[7] = xp[4032]; // x[63][0]
    o[8] = xp[4095]; // x[63][63]
  }
}

// ---------------- fused modulation gate: one block per batch element ----------------
__global__ __launch_bounds__(256) void k_gate(const float* __restrict__ dce,
    const float* __restrict__ stats, const float* __restrict__ wch,
    const float* __restrict__ w_dce, const float* __restrict__ b_dce,
    const float* __restrict__ w_sh, const float* __restrict__ b_sh,
    const float* __restrict__ w_ex, const float* __restrict__ b_ex,
    float* __restrict__ modb){
  int b = blockIdx.x, tid = threadIdx.x;
  __shared__ float pl[128];
  __shared__ float mbuf[256];
  __shared__ float hbuf[128];
  __shared__ float ptmp[256];
  {
    int k = tid & 127, half = tid >> 7;
    const float* p = dce + (size_t)b*12800 + half*50*128 + k;
    float s = 0.f;
    #pragma unroll 5
    for (int l=0;l<50;l++) s += p[l*128];
    ptmp[tid] = s;
  }
  __syncthreads();
  if (tid < 128) pl[tid] = (ptmp[tid] + ptmp[tid+128]) * 0.01f;
  __syncthreads();
  {
    int c = tid;
    const float* st = stats + (size_t)(b*256+c)*9;
    float S=st[0], r0=st[1], r1=st[2], cc0=st[3], cc1=st[4];
    float x00=st[5], x0W=st[6], xH0=st[7], xHW=st[8];
    float acc = 0.f;
    #pragma unroll
    for (int t=0;t<9;t++){
      int dh = t/3 - 1, dw = t%3 - 1;
      float R = (dh==1)? r0 : (dh==-1)? r1 : 0.f;
      float Cc = (dw==1)? cc0 : (dw==-1)? cc1 : 0.f;
      float X = 0.f;
      if (dh==1 && dw==1) X = x00;
      else if (dh==1 && dw==-1) X = x0W;
      else if (dh==-1 && dw==1) X = xH0;
      else if (dh==-1 && dw==-1) X = xHW;
      acc += wch[c*9+t] * (S - R - Cc + X);
    }
    float sp_ = acc * (1.f/4096.f);
    float dp = b_dce[c];
    const float4* wr = (const float4*)(w_dce + c*128);
    #pragma unroll 8
    for (int k4=0;k4<32;k4++){
      float4 w4 = wr[k4];
      dp += w4.x*pl[k4*4] + w4.y*pl[k4*4+1] + w4.z*pl[k4*4+2] + w4.w*pl[k4*4+3];
    }
    mbuf[c] = sp_ * dp;
  }
  __syncthreads();
  if (tid < 128){
    int j = tid;
    float acc = b_sh[j];
    const float4* wr = (const float4*)(w_sh + j*256);
    #pragma unroll 8
    for (int k4=0;k4<64;k4++){
      float4 w4 = wr[k4];
      acc += w4.x*mbuf[k4*4] + w4.y*mbuf[k4*4+1] + w4.z*mbuf[k4*4+2] + w4.w*mbuf[k4*4+3];
    }
    hbuf[j] = fmaxf(acc, 0.f);
  }
  __syncthreads();
  {
    int c = tid;
    float acc = b_ex[c];
    const float4* wr = (const float4*)(w_ex + c*128);
    #pragma unroll 8
    for (int k4=0;k4<32;k4++){
      float4 w4 = wr[k4];
      acc += w4.x*hbuf[k4*4] + w4.y*hbuf[k4*4+1] + w4.z*hbuf[k4*4+2] + w4.w*hbuf[k4*4+3];
    }
    modb[b*256+c] = 1.f/(1.f + __expf(-acc));
  }
}

// ---------------- merged weight transforms to bf16 ----------------
__global__ __launch_bounds__(256) void k_wprep(const float* __restrict__ w1,
    const float* __restrict__ wsc, const float* __restrict__ w2,
    u16* __restrict__ w1t, u16* __restrict__ wsct, u16* __restrict__ w2t){
  int bx = blockIdx.x, ci = threadIdx.x;
  if (bx < 2304){
    int co = bx / 9, t = bx - co*9;
    w1t[(size_t)co*2304 + t*256 + ci] = f2bf(w1[(size_t)(co*256+ci)*9 + t]);
  } else if (bx < 2560){
    int i = (bx-2304)*256 + ci;
    wsct[i] = f2bf(wsc[i]);
  } else {
    int i = (bx-2560)*256 + ci;
    w2t[i] = f2bf(w2[i]);
  }
}

// ---------------- xm = x*mod, NCHW f32 -> NHWC bf16 ----------------
__global__ __launch_bounds__(256) void k_xm(const float* __restrict__ x, const float* __restrict__ modb,
                                            u16* __restrict__ xm){
  __shared__ __attribute__((aligned(16))) u16 tile[64*266];
  int pt = blockIdx.x, ct = blockIdx.y, tid = threadIdx.x;
  size_t P0 = (size_t)pt * 256;
  int b = pt >> 4;
  int rem = (pt & 15) << 8;
  int C0 = ct << 6;
  {
    int c = tid >> 2, q = tid & 3;
    const float* xp = x + ((size_t)(b*256 + C0 + c))*HW + rem;
    float mv = modb[b*256 + C0 + c];
    #pragma unroll
    for (int k=0;k<16;k++){
      int pos = q*64 + k*4;
      float4 v = *(const float4*)(xp + pos);
      u32 w0 = (u32)f2bf(v.x*mv) | ((u32)f2bf(v.y*mv) << 16);
      u32 w1 = (u32)f2bf(v.z*mv) | ((u32)f2bf(v.w*mv) << 16);
      u32* dst = (u32*)&tile[c*266 + pos];
      dst[0] = w0; dst[1] = w1;
    }
  }
  __syncthreads();
  {
    int g = tid & 7, p0 = tid >> 3;
    #pragma unroll
    for (int k=0;k<8;k++){
      int pos = p0 + k*32;
      u32 v0 = tile[(g*8+0)*266 + pos], v1 = tile[(g*8+1)*266 + pos];
      u32 v2 = tile[(g*8+2)*266 + pos], v3 = tile[(g*8+3)*266 + pos];
      u32 v4 = tile[(g*8+4)*266 + pos], v5 = tile[(g*8+5)*266 + pos];
      u32 v6 = tile[(g*8+6)*266 + pos], v7 = tile[(g*8+7)*266 + pos];
      uint4 pk;
      pk.x = v0 | (v1<<16); pk.y = v2 | (v3<<16);
      pk.z = v4 | (v5<<16); pk.w = v6 | (v7<<16);
      *(uint4*)(xm + (P0+pos)*CH + C0 + g*8) = pk;
    }
  }
}

// ---------------- GEMM epilogue: store y bf16 + per-mtile channel partials ----------------
// psum/psq layout: [channel][mtile] (MT stride) so k_bnstat reads coalesced.
__device__ __forceinline__ void epilogue_store(f32x4 (&acc)[4][4], int P0, int N0, int wm, int wn,
    int l15, int quad, int tid, int mt_blk, u16* __restrict__ y,
    float* __restrict__ psum, float* __restrict__ psq, float* redbuf){
  #pragma unroll
  for (int i=0;i<4;i++){
    int m = wm*64 + i*16 + quad*4;
    #pragma unroll
    for (int j=0;j<4;j++){
      int n = wn*64 + j*16 + l15;
      size_t base = ((size_t)(P0 + m))*CH + N0 + n;
      #pragma unroll
      for (int r=0;r<4;r++)
        y[base + (size_t)r*CH] = f2bf(acc[i][j][r]);
    }
  }
  #pragma unroll
  for (int j=0;j<4;j++){
    float a=0.f, b=0.f;
    #pragma unroll
    for (int i=0;i<4;i++)
      #pragma unroll
      for (int r=0;r<4;r++){ float v = acc[i][j][r]; a += v; b += v*v; }
    a += __shfl_xor(a,16); b += __shfl_xor(b,16);
    a += __shfl_xor(a,32); b += __shfl_xor(b,32);
    if (quad==0){
      int idx = (((wn*2+wm)*4 + j)*16 + l15)*2;
      redbuf[idx] = a; redbuf[idx+1] = b;
    }
  }
  __syncthreads();
  if (tid < 128){
    int n = tid; int wnn = n>>6, ntj=(n>>4)&3, li=n&15;
    int i0 = (((wnn*2+0)*4 + ntj)*16 + li)*2;
    int i1 = (((wnn*2+1)*4 + ntj)*16 + li)*2;
    psum[(size_t)(N0 + n)*MT + mt_blk] = redbuf[i0]   + redbuf[i1];
    psq [(size_t)(N0 + n)*MT + mt_blk] = redbuf[i0+1] + redbuf[i1+1];
  }
}

// ---------------- conv3x3 implicit GEMM, K=64 per barrier, dbuf ----------------
__global__ __launch_bounds__(256) void k_conv3(const u16* __restrict__ xm, const u16* __restrict__ w1t,
    u16* __restrict__ y, float* __restrict__ psum, float* __restrict__ psq, const u16* __restrict__ zp){
  __shared__ __attribute__((aligned(16))) u16 As[4*4096];
  __shared__ __attribute__((aligned(16))) u16 Bs[4*4096];
  __shared__ __attribute__((aligned(16))) float redbuf[512];
  int bx = blockIdx.x;
  int mt_blk = ((bx >> 4) << 3) | (bx & 7);
  int nt_blk = (bx >> 3) & 1;
  int tid = threadIdx.x;
  int lane = tid & 63, wave = tid >> 6;
  int wm = wave & 1, wn = wave >> 1;
  int l15 = lane & 15, quad = lane >> 4;
  int P0 = mt_blk*128, N0 = nt_blk*128;
  int prow = tid >> 2, cg = tid & 3;
  int swzw = (cg ^ (prow & 3) ^ ((prow >> 2) & 3)) * 8;
  int wr0 = prow*32 + swzw;
  int wr1 = (prow+64)*32 + swzw;
  int rdsw = (quad ^ (l15 & 3) ^ ((l15 >> 2) & 3)) * 8;
  int rA[4], rB[4];
  #pragma unroll
  for (int i=0;i<4;i++){
    rA[i] = (wm*64 + i*16 + l15)*32 + rdsw;
    rB[i] = (wn*64 + i*16 + l15)*32 + rdsw;
  }
  const u16* b0base = w1t + (size_t)(N0 + prow)*2304 + cg*8;
  const u16* b1base = w1t + (size_t)(N0 + prow + 64)*2304 + cg*8;
  int P_0 = P0 + prow, P_1 = P0 + prow + 64;
  int h_0 = (P_0 >> 6) & 63, w_0 = P_0 & 63, bi0 = P_0 >> 12;
  int h_1 = (P_1 >> 6) & 63, w_1 = P_1 & 63, bi1 = P_1 >> 12;

  f32x4 acc[4][4];
  f32x4 zz = {0.f,0.f,0.f,0.f};
  #pragma unroll
  for (int i=0;i<4;i++)
    #pragma unroll
    for (int j=0;j<4;j++) acc[i][j] = zz;

  auto aptr0 = [&](int t)->const u16*{
    int dh = t/3 - 1, dw = t%3 - 1;
    int h2 = h_0 + dh, w2 = w_0 + dw;
    return (((unsigned)h2 < 64u) && ((unsigned)w2 < 64u))
        ? xm + (((size_t)bi0*HW + h2*64 + w2)*CH) + cg*8 : zp + cg*8;
  };
  auto aptr1 = [&](int t)->const u16*{
    int dh = t/3 - 1, dw = t%3 - 1;
    int h2 = h_1 + dh, w2 = w_1 + dw;
    return (((unsigned)h2 < 64u) && ((unsigned)w2 < 64u))
        ? xm + (((size_t)bi1*HW + h2*64 + w2)*CH) + cg*8 : zp + cg*8;
  };

  const u16 *pa0 = aptr0(0), *pa1 = aptr1(0);
  const u16 *pb0 = b0base,   *pb1 = b1base;
  uint4 ra0[2], ra1[2], rb0[2], rb1[2];
  ra0[0] = *(const uint4*)pa0;        ra0[1] = *(const uint4*)(pa0+32);
  ra1[0] = *(const uint4*)pa1;        ra1[1] = *(const uint4*)(pa1+32);
  rb0[0] = *(const uint4*)pb0;        rb0[1] = *(const uint4*)(pb0+32);
  rb1[0] = *(const uint4*)pb1;        rb1[1] = *(const uint4*)(pb1+32);

  // 72 K32 chunks = 36 pairs; one barrier per 64-K pair
  for (int p=0; p<36; p++){
    const int par = p & 1;
    u16* A0 = As + (par*2)*4096;  u16* A1 = A0 + 4096;
    u16* B0 = Bs + (par*2)*4096;  u16* B1 = B0 + 4096;
    *(uint4*)(A0+wr0) = ra0[0];  *(uint4*)(A1+wr0) = ra0[1];
    *(uint4*)(A0+wr1) = ra1[0];  *(uint4*)(A1+wr1) = ra1[1];
    *(uint4*)(B0+wr0) = rb0[0];  *(uint4*)(B1+wr0) = rb0[1];
    *(uint4*)(B0+wr1) = rb1[0];  *(uint4*)(B1+wr1) = rb1[1];
    __syncthreads();
    if (p < 35){
      int cc = 2*p + 2;
      if ((cc & 7) == 0){
        int t = cc >> 3;
        pa0 = aptr0(t); pa1 = aptr1(t);
        pb0 = b0base + t*256; pb1 = b1base + t*256;
      }
      int o0 = (cc & 7)*32, o1 = o0 + 32;
      ra0[0] = *(const uint4*)(pa0+o0);  ra0[1] = *(const uint4*)(pa0+o1);
      ra1[0] = *(const uint4*)(pa1+o0);  ra1[1] = *(const uint4*)(pa1+o1);
      rb0[0] = *(const uint4*)(pb0+o0);  rb0[1] = *(const uint4*)(pb0+o1);
      rb1[0] = *(const uint4*)(pb1+o0);  rb1[1] = *(const uint4*)(pb1+o1);
    }
    #pragma unroll
    for (int kc=0; kc<2; kc++){
      const u16* Ab = As + (par*2 + kc)*4096;
      const u16* Bb = Bs + (par*2 + kc)*4096;
      bf16x8 af[4], bv[4];
      #pragma unroll
      for (int i=0;i<4;i++) af[i] = *(const bf16x8*)&Ab[rA[i]];
      #pragma unroll
      for (int i=0;i<4;i++) bv[i] = *(const bf16x8*)&Bb[rB[i]];
      #pragma unroll
      for (int i=0;i<4;i++)
        #pragma unroll
        for (int j=0;j<4;j++)
          acc[i][j] = __builtin_amdgcn_mfma_f32_16x16x32_bf16(af[i], bv[j], acc[i][j], 0, 0, 0);
    }
  }
  epilogue_store(acc, P0, N0, wm, wn, l15, quad, tid, mt_blk, y, psum, psq, redbuf);
}

// ---------------- 1x1 conv GEMM (sc and conv2), K=64 per barrier ----------------
__global__ __launch_bounds__(256) void k_gemm1x1(const u16* __restrict__ A, const u16* __restrict__ Bw,
    u16* __restrict__ y, float* __restrict__ psum, float* __restrict__ psq){
  __shared__ __attribute__((aligned(16))) u16 As[4*4096];
  __shared__ __attribute__((aligned(16))) u16 Bs[4*4096];
  __shared__ __attribute__((aligned(16))) float redbuf[512];
  int bx = blockIdx.x;
  int mt_blk = ((bx >> 4) << 3) | (bx & 7);
  int nt_blk = (bx >> 3) & 1;
  int tid = threadIdx.x;
  int lane = tid & 63, wave = tid >> 6;
  int wm = wave & 1, wn = wave >> 1;
  int l15 = lane & 15, quad = lane >> 4;
  int P0 = mt_blk*128, N0 = nt_blk*128;
  int prow = tid >> 2, cg = tid & 3;
  int swzw = (cg ^ (prow & 3) ^ ((prow >> 2) & 3)) * 8;
  int wr0 = prow*32 + swzw;
  int wr1 = (prow+64)*32 + swzw;
  int rdsw = (quad ^ (l15 & 3) ^ ((l15 >> 2) & 3)) * 8;
  int rA[4], rB[4];
  #pragma unroll
  for (int i=0;i<4;i++){
    rA[i] = (wm*64 + i*16 + l15)*32 + rdsw;
    rB[i] = (wn*64 + i*16 + l15)*32 + rdsw;
  }
  const u16* a0p = A  + ((size_t)(P0 + prow))*CH + cg*8;
  const u16* a1p = A  + ((size_t)(P0 + prow + 64))*CH + cg*8;
  const u16* b0p = Bw + ((size_t)(N0 + prow))*CH + cg*8;
  const u16* b1p = Bw + ((size_t)(N0 + prow + 64))*CH + cg*8;
  f32x4 acc[4][4];
  f32x4 zz = {0.f,0.f,0.f,0.f};
  #pragma unroll
  for (int i=0;i<4;i++)
    #pragma unroll
    for (int j=0;j<4;j++) acc[i][j] = zz;

  uint4 ra0[2], ra1[2], rb0[2], rb1[2];
  ra0[0] = *(const uint4*)a0p;   ra0[1] = *(const uint4*)(a0p+32);
  ra1[0] = *(const uint4*)a1p;   ra1[1] = *(const uint4*)(a1p+32);
  rb0[0] = *(const uint4*)b0p;   rb0[1] = *(const uint4*)(b0p+32);
  rb1[0] = *(const uint4*)b1p;   rb1[1] = *(const uint4*)(b1p+32);

  #pragma unroll
  for (int p=0; p<4; p++){
    const int par = p & 1;
    u16* A0 = As + (par*2)*4096;  u16* A1 = A0 + 4096;
    u16* B0 = Bs + (par*2)*4096;  u16* B1 = B0 + 4096;
    *(uint4*)(A0+wr0) = ra0[0];  *(uint4*)(A1+wr0) = ra0[1];
    *(uint4*)(A0+wr1) = ra1[0];  *(uint4*)(A1+wr1) = ra1[1];
    *(uint4*)(B0+wr0) = rb0[0];  *(uint4*)(B1+wr0) = rb0[1];
    *(uint4*)(B0+wr1) = rb1[0];  *(uint4*)(B1+wr1) = rb1[1];
    __syncthreads();
    if (p < 3){
      int o0 = (2*p+2)*32, o1 = o0 + 32;
      ra0[0] = *(const uint4*)(a0p+o0);  ra0[1] = *(const uint4*)(a0p+o1);
      ra1[0] = *(const uint4*)(a1p+o0);  ra1[1] = *(const uint4*)(a1p+o1);
      rb0[0] = *(const uint4*)(b0p+o0);  rb0[1] = *(const uint4*)(b0p+o1);
      rb1[0] = *(const uint4*)(b1p+o0);  rb1[1] = *(const uint4*)(b1p+o1);
    }
    #pragma unroll
    for (int kc=0; kc<2; kc++){
      const u16* Ab = As + (par*2 + kc)*4096;
      const u16* Bb = Bs + (par*2 + kc)*4096;
      bf16x8 af[4], bv[4];
      #pragma unroll
      for (int i=0;i<4;i++) af[i] = *(const bf16x8*)&Ab[rA[i]];
      #pragma unroll
      for (int i=0;i<4;i++) bv[i] = *(const bf16x8*)&Bb[rB[i]];
      #pragma unroll
      for (int i=0;i<4;i++)
        #pragma unroll
        for (int j=0;j<4;j++)
          acc[i][j] = __builtin_amdgcn_mfma_f32_16x16x32_bf16(af[i], bv[j], acc[i][j], 0, 0, 0);
    }
  }
  epilogue_store(acc, P0, N0, wm, wn, l15, quad, tid, mt_blk, y, psum, psq, redbuf);
}

// ---------------- BN stat finalize: one block per channel, coalesced ----------------
__global__ __launch_bounds__(64) void k_bnstat(const float* __restrict__ psum, const float* __restrict__ psq,
    const float* __restrict__ g, const float* __restrict__ be,
    float* __restrict__ scale, float* __restrict__ shift){
  int c = blockIdx.x, t = threadIdx.x;
  const float* ps = psum + (size_t)c*MT;
  const float* pq = psq  + (size_t)c*MT;
  float s=0.f, q=0.f;
  #pragma unroll
  for (int i=0;i<8;i++){ s += ps[t + i*64]; q += pq[t + i*64]; }
  #pragma unroll
  for (int off=32; off>0; off>>=1){
    s += __shfl_down(s, off);
    q += __shfl_down(q, off);
  }
  if (t == 0){
    float mean = s * (1.f/65536.f);
    float var  = q * (1.f/65536.f) - mean*mean;
    float rstd = rsqrtf(var + 1e-5f);
    float sc = g[c]*rstd;
    scale[c] = sc;
    shift[c] = be[c] - mean*sc;
  }
}

// ---------------- bb1 = silu(bn1(y1)) elementwise on NHWC bf16 ----------------
__global__ __launch_bounds__(256) void k_bb(const u16* __restrict__ y1, const float* __restrict__ sc1,
    const float* __restrict__ sh1, u16* __restrict__ bb){
  __shared__ float sc[256], sh[256];
  int tid = threadIdx.x;
  sc[tid] = sc1[tid]; sh[tid] = sh1[tid];
  __syncthreads();
  size_t i = ((size_t)blockIdx.x*256 + tid)*8;
  int c0 = (int)(i & 255);
  uint4 v = *(const uint4*)(y1 + i);
  u32 a[4] = {v.x, v.y, v.z, v.w};
  u32 o[4];
  #pragma unroll
  for (int p=0;p<4;p++){
    float zl = sc[c0+2*p]*bflo(a[p]) + sh[c0+2*p];
    float zh = sc[c0+2*p+1]*bfhi(a[p]) + sh[c0+2*p+1];
    float ol = zl/(1.f+__expf(-zl));
    float oh = zh/(1.f+__expf(-zh));
    o[p] = (u32)f2bf(ol) | ((u32)f2bf(oh) << 16);
  }
  uint4 w; w.x=o[0]; w.y=o[1]; w.z=o[2]; w.w=o[3];
  *(uint4*)(bb + i) = w;
}

// ---------------- out = silu(bn2(y2)+bns(ysc)), NHWC bf16 -> NCHW f32 ----------------
__global__ __launch_bounds__(256) void k_final(const u16* __restrict__ y2, const u16* __restrict__ ysc,
    const float* __restrict__ sc2, const float* __restrict__ sh2,
    const float* __restrict__ scs, const float* __restrict__ shs,
    float* __restrict__ out){
  __shared__ __attribute__((aligned(16))) float tile[64*257];
  __shared__ float l2s[64], l2h[64], lss[64], lsh[64];
  int pt = blockIdx.x, ct = blockIdx.y, tid = threadIdx.x;
  int C0 = ct << 6;
  if (tid < 64){ l2s[tid]=sc2[C0+tid]; l2h[tid]=sh2[C0+tid]; lss[tid]=scs[C0+tid]; lsh[tid]=shs[C0+tid]; }
  __syncthreads();
  size_t P0 = (size_t)pt * 256;
  int b = pt >> 4; int rem = (pt & 15) << 8;
  {
    int g = tid & 7, p0 = tid >> 3;
    for (int k=0;k<8;k++){
      int pos = p0 + k*32;
      size_t off = (P0+pos)*CH + C0 + g*8;
      uint4 va = *(const uint4*)(y2 + off);
      uint4 vb = *(const uint4*)(ysc + off);
      u32 aa[4] = {va.x,va.y,va.z,va.w};
      u32 bv[4] = {vb.x,vb.y,vb.z,vb.w};
      #pragma unroll
      for (int p=0;p<4;p++){
        int c = g*8 + 2*p;
        float z0 = l2s[c]*bflo(aa[p]) + l2h[c] + lss[c]*bflo(bv[p]) + lsh[c];
        float z1 = l2s[c+1]*bfhi(aa[p]) + l2h[c+1] + lss[c+1]*bfhi(bv[p]) + lsh[c+1];
        tile[c*257 + pos]     = z0/(1.f+__expf(-z0));
        tile[(c+1)*257 + pos] = z1/(1.f+__expf(-z1));
      }
    }
  }
  __syncthreads();
  {
    int c = tid >> 2, q = tid & 3;
    float* op = out + ((size_t)(b*256 + C0 + c))*HW + rem;
    #pragma unroll
    for (int k=0;k<16;k++){
      int pos = q*64 + k*4;
      float4 v;
      v.x = tile[c*257 + pos];
      v.y = tile[c*257 + pos + 1];
      v.z = tile[c*257 + pos + 2];
      v.w = tile[c*257 + pos + 3];
      *(float4*)(op + pos) = v;
    }
  }
}

extern "C" void kernel_launch(void* const* d_in, const int* in_sizes, int n_in,
                              void* d_out, int out_size, void* d_ws, size_t ws_size,
                              hipStream_t stream){
  const float* x     = (const float*)d_in[0];
  const float* dce   = (const float*)d_in[1];
  const float* w_dce = (const float*)d_in[2];
  const float* b_dce = (const float*)d_in[3];
  const float* w_ch  = (const float*)d_in[4];
  const float* w_sh  = (const float*)d_in[5];
  const float* b_sh  = (const float*)d_in[6];
  const float* w_ex  = (const float*)d_in[7];
  const float* b_ex  = (const float*)d_in[8];
  const float* w_c1  = (const float*)d_in[9];
  const float* g1    = (const float*)d_in[10];
  const float* be1   = (const float*)d_in[11];
  const float* w_c2  = (const float*)d_in[12];
  const float* g2    = (const float*)d_in[13];
  const float* be2   = (const float*)d_in[14];
  const float* w_s   = (const float*)d_in[15];
  const float* gs    = (const float*)d_in[16];
  const float* bes   = (const float*)d_in[17];
  float* out = (float*)d_out;
  char* ws = (char*)d_ws;

  const size_t NB = (size_t)NPOS*CH*2;   // 32 MiB per bf16 tensor
  u16* xm  = (u16*)(ws);
  u16* y1  = (u16*)(ws + NB);
  u16* ysc = (u16*)(ws + 2*NB);
  u16* bb  = (u16*)(ws + 3*NB);
  char* p = ws + 4*NB;
  u16* w1t   = (u16*)p; p += (size_t)256*2304*2;
  u16* wsct  = (u16*)p; p += (size_t)256*256*2;
  u16* w2t   = (u16*)p; p += (size_t)256*256*2;
  float* statsx = (float*)p; p += (size_t)16*256*9*4;
  float* modb   = (float*)p; p += (size_t)16*256*4;
  float* p1s = (float*)p; p += (size_t)MT*256*4;
  float* p1q = (float*)p; p += (size_t)MT*256*4;
  float* pss = (float*)p; p += (size_t)MT*256*4;
  float* psqv= (float*)p; p += (size_t)MT*256*4;
  float* p2s = (float*)p; p += (size_t)MT*256*4;
  float* p2q = (float*)p; p += (size_t)MT*256*4;
  float* bn1sc = (float*)p; p += 1024;
  float* bn1sh = (float*)p; p += 1024;
  float* bnssc = (float*)p; p += 1024;
  float* bnssh = (float*)p; p += 1024;
  float* bn2sc = (float*)p; p += 1024;
  float* bn2sh = (float*)p; p += 1024;
  u16* zp = (u16*)p; p += 4096;

  hipMemsetAsync(zp, 0, 4096, stream);
  k_statsx<<<4096, 256, 0, stream>>>(x, statsx);
  k_wprep<<<2816, 256, 0, stream>>>(w_c1, w_s, w_c2, w1t, wsct, w2t);
  k_gate<<<16, 256, 0, stream>>>(dce, statsx, w_ch, w_dce, b_dce, w_sh, b_sh, w_ex, b_ex, modb);
  k_xm<<<dim3(256,4), 256, 0, stream>>>(x, modb, xm);
  k_conv3<<<1024, 256, 0, stream>>>(xm, w1t, y1, p1s, p1q, zp);
  k_bnstat<<<256, 64, 0, stream>>>(p1s, p1q, g1, be1, bn1sc, bn1sh);
  k_bb<<<8192, 256, 0, stream>>>(y1, bn1sc, bn1sh, bb);
  k_gemm1x1<<<1024, 256, 0, stream>>>(xm, wsct, ysc, pss, psqv);
  k_bnstat<<<256, 64, 0, stream>>>(pss, psqv, gs, bes, bnssc, bnssh);
  k_gemm1x1<<<1024, 256, 0, stream>>>(bb, w2t, y1 /*=y2*/, p2s, p2q);
  k_bnstat<<<256, 64, 0, stream>>>(p2s, p2q, g2, be2, bn2sc, bn2sh);
  k_final<<<dim3(256,4), 256, 0, stream>>>(y1, ysc, bn2sc, bn2sh, bnssc, bnssh, out);
}

// Round 6
// 432.639 us; speedup vs baseline: 1.3869x; 1.3869x over previous
//
#include <hip/hip_runtime.h>

typedef unsigned short u16;
typedef unsigned int   u32;
typedef __attribute__((ext_vector_type(8))) __bf16 bf16x8;
typedef __attribute__((ext_vector_type(4))) float  f32x4;

#define HW 4096
#define NPOS 65536
#define CH 256
#define MT 512   // number of 128-row M tiles

__device__ __forceinline__ u16 f2bf(float f){
  u32 u = __float_as_uint(f);
  u += 0x7FFFu + ((u >> 16) & 1u);
  return (u16)(u >> 16);
}
__device__ __forceinline__ float bflo(u32 p){ return __uint_as_float(p << 16); }
__device__ __forceinline__ float bfhi(u32 p){ return __uint_as_float(p & 0xFFFF0000u); }

// ---------------- x plane stats: total, edge rows/cols, corners ----------------
__global__ __launch_bounds__(256) void k_statsx(const float* __restrict__ x, float* __restrict__ stats){
  int bc = blockIdx.x; int tid = threadIdx.x;
  const float* xp = x + (size_t)bc * HW;
  float S=0.f, r0=0.f, r1=0.f, c0=0.f, c1=0.f;
  #pragma unroll
  for (int k=0;k<4;k++){
    int i4 = tid + k*256;
    float4 v = ((const float4*)xp)[i4];
    int pos = i4*4; int h = pos>>6; int wb = pos&63;
    float sv = v.x+v.y+v.z+v.w;
    S += sv;
    if (h==0)  r0 += sv;
    if (h==63) r1 += sv;
    if (wb==0)  c0 += v.x;
    if (wb==60) c1 += v.w;
  }
  __shared__ float red[4][5];
  #pragma unroll
  for (int off=32; off>0; off>>=1){
    S  += __shfl_down(S, off);
    r0 += __shfl_down(r0, off);
    r1 += __shfl_down(r1, off);
    c0 += __shfl_down(c0, off);
    c1 += __shfl_down(c1, off);
  }
  if ((tid & 63) == 0){
    int w = tid >> 6;
    red[w][0]=S; red[w][1]=r0; red[w][2]=r1; red[w][3]=c0; red[w][4]=c1;
  }
  __syncthreads();
  if (tid == 0){
    float* o = stats + (size_t)bc * 9;
    for (int j=0;j<5;j++) o[j] = red[0][j]+red[1][j]+red[2][j]+red[3][j];
    o[5] = xp[0];    // x[0][0]
    o[6] = xp[63];   // x[0][63]
    o[7] = xp[4032]; // x[63][0]
    o[8] = xp[4095]; // x[63][63]
  }
}

// ---------------- fused modulation gate: one block per batch element ----------------
__global__ __launch_bounds__(256) void k_gate(const float* __restrict__ dce,
    const float* __restrict__ stats, const float* __restrict__ wch,
    const float* __restrict__ w_dce, const float* __restrict__ b_dce,
    const float* __restrict__ w_sh, const float* __restrict__ b_sh,
    const float* __restrict__ w_ex, const float* __restrict__ b_ex,
    float* __restrict__ modb){
  int b = blockIdx.x, tid = threadIdx.x;
  __shared__ float pl[128];
  __shared__ float mbuf[256];
  __shared__ float hbuf[128];
  __shared__ float ptmp[256];
  {
    int k = tid & 127, half = tid >> 7;
    const float* p = dce + (size_t)b*12800 + half*50*128 + k;
    float s = 0.f;
    #pragma unroll 5
    for (int l=0;l<50;l++) s += p[l*128];
    ptmp[tid] = s;
  }
  __syncthreads();
  if (tid < 128) pl[tid] = (ptmp[tid] + ptmp[tid+128]) * 0.01f;
  __syncthreads();
  {
    int c = tid;
    const float* st = stats + (size_t)(b*256+c)*9;
    float S=st[0], r0=st[1], r1=st[2], cc0=st[3], cc1=st[4];
    float x00=st[5], x0W=st[6], xH0=st[7], xHW=st[8];
    float acc = 0.f;
    #pragma unroll
    for (int t=0;t<9;t++){
      int dh = t/3 - 1, dw = t%3 - 1;
      float R = (dh==1)? r0 : (dh==-1)? r1 : 0.f;
      float Cc = (dw==1)? cc0 : (dw==-1)? cc1 : 0.f;
      float X = 0.f;
      if (dh==1 && dw==1) X = x00;
      else if (dh==1 && dw==-1) X = x0W;
      else if (dh==-1 && dw==1) X = xH0;
      else if (dh==-1 && dw==-1) X = xHW;
      acc += wch[c*9+t] * (S - R - Cc + X);
    }
    float sp_ = acc * (1.f/4096.f);
    float dp = b_dce[c];
    const float4* wr = (const float4*)(w_dce + c*128);
    #pragma unroll 8
    for (int k4=0;k4<32;k4++){
      float4 w4 = wr[k4];
      dp += w4.x*pl[k4*4] + w4.y*pl[k4*4+1] + w4.z*pl[k4*4+2] + w4.w*pl[k4*4+3];
    }
    mbuf[c] = sp_ * dp;
  }
  __syncthreads();
  if (tid < 128){
    int j = tid;
    float acc = b_sh[j];
    const float4* wr = (const float4*)(w_sh + j*256);
    #pragma unroll 8
    for (int k4=0;k4<64;k4++){
      float4 w4 = wr[k4];
      acc += w4.x*mbuf[k4*4] + w4.y*mbuf[k4*4+1] + w4.z*mbuf[k4*4+2] + w4.w*mbuf[k4*4+3];
    }
    hbuf[j] = fmaxf(acc, 0.f);
  }
  __syncthreads();
  {
    int c = tid;
    float acc = b_ex[c];
    const float4* wr = (const float4*)(w_ex + c*128);
    #pragma unroll 8
    for (int k4=0;k4<32;k4++){
      float4 w4 = wr[k4];
      acc += w4.x*hbuf[k4*4] + w4.y*hbuf[k4*4+1] + w4.z*hbuf[k4*4+2] + w4.w*hbuf[k4*4+3];
    }
    modb[b*256+c] = 1.f/(1.f + __expf(-acc));
  }
}

// ---------------- merged weight transforms to bf16 ----------------
__global__ __launch_bounds__(256) void k_wprep(const float* __restrict__ w1,
    const float* __restrict__ wsc, const float* __restrict__ w2,
    u16* __restrict__ w1t, u16* __restrict__ wsct, u16* __restrict__ w2t){
  int bx = blockIdx.x, ci = threadIdx.x;
  if (bx < 2304){
    int co = bx / 9, t = bx - co*9;
    w1t[(size_t)co*2304 + t*256 + ci] = f2bf(w1[(size_t)(co*256+ci)*9 + t]);
  } else if (bx < 2560){
    int i = (bx-2304)*256 + ci;
    wsct[i] = f2bf(wsc[i]);
  } else {
    int i = (bx-2560)*256 + ci;
    w2t[i] = f2bf(w2[i]);
  }
}

// ---------------- xm = x*mod, NCHW f32 -> NHWC bf16 ----------------
__global__ __launch_bounds__(256) void k_xm(const float* __restrict__ x, const float* __restrict__ modb,
                                            u16* __restrict__ xm){
  __shared__ __attribute__((aligned(16))) u16 tile[64*266];
  int pt = blockIdx.x, ct = blockIdx.y, tid = threadIdx.x;
  size_t P0 = (size_t)pt * 256;
  int b = pt >> 4;
  int rem = (pt & 15) << 8;
  int C0 = ct << 6;
  {
    int c = tid >> 2, q = tid & 3;
    const float* xp = x + ((size_t)(b*256 + C0 + c))*HW + rem;
    float mv = modb[b*256 + C0 + c];
    #pragma unroll
    for (int k=0;k<16;k++){
      int pos = q*64 + k*4;
      float4 v = *(const float4*)(xp + pos);
      u32 w0 = (u32)f2bf(v.x*mv) | ((u32)f2bf(v.y*mv) << 16);
      u32 w1 = (u32)f2bf(v.z*mv) | ((u32)f2bf(v.w*mv) << 16);
      u32* dst = (u32*)&tile[c*266 + pos];
      dst[0] = w0; dst[1] = w1;
    }
  }
  __syncthreads();
  {
    int g = tid & 7, p0 = tid >> 3;
    #pragma unroll
    for (int k=0;k<8;k++){
      int pos = p0 + k*32;
      u32 v0 = tile[(g*8+0)*266 + pos], v1 = tile[(g*8+1)*266 + pos];
      u32 v2 = tile[(g*8+2)*266 + pos], v3 = tile[(g*8+3)*266 + pos];
      u32 v4 = tile[(g*8+4)*266 + pos], v5 = tile[(g*8+5)*266 + pos];
      u32 v6 = tile[(g*8+6)*266 + pos], v7 = tile[(g*8+7)*266 + pos];
      uint4 pk;
      pk.x = v0 | (v1<<16); pk.y = v2 | (v3<<16);
      pk.z = v4 | (v5<<16); pk.w = v6 | (v7<<16);
      *(uint4*)(xm + (P0+pos)*CH + C0 + g*8) = pk;
    }
  }
}

// ---------------- GEMM epilogue: store y bf16 + per-mtile channel partials ----------------
// psum/psq layout: [channel][mtile] (MT stride) so k_bnstat reads coalesced.
__device__ __forceinline__ void epilogue_store(f32x4 (&acc)[4][4], int P0, int N0, int wm, int wn,
    int l15, int quad, int tid, int mt_blk, u16* __restrict__ y,
    float* __restrict__ psum, float* __restrict__ psq, float* redbuf){
  #pragma unroll
  for (int i=0;i<4;i++){
    int m = wm*64 + i*16 + quad*4;
    #pragma unroll
    for (int j=0;j<4;j++){
      int n = wn*64 + j*16 + l15;
      size_t base = ((size_t)(P0 + m))*CH + N0 + n;
      #pragma unroll
      for (int r=0;r<4;r++)
        y[base + (size_t)r*CH] = f2bf(acc[i][j][r]);
    }
  }
  #pragma unroll
  for (int j=0;j<4;j++){
    float a=0.f, b=0.f;
    #pragma unroll
    for (int i=0;i<4;i++)
      #pragma unroll
      for (int r=0;r<4;r++){ float v = acc[i][j][r]; a += v; b += v*v; }
    a += __shfl_xor(a,16); b += __shfl_xor(b,16);
    a += __shfl_xor(a,32); b += __shfl_xor(b,32);
    if (quad==0){
      int idx = (((wn*2+wm)*4 + j)*16 + l15)*2;
      redbuf[idx] = a; redbuf[idx+1] = b;
    }
  }
  __syncthreads();
  if (tid < 128){
    int n = tid; int wnn = n>>6, ntj=(n>>4)&3, li=n&15;
    int i0 = (((wnn*2+0)*4 + ntj)*16 + li)*2;
    int i1 = (((wnn*2+1)*4 + ntj)*16 + li)*2;
    psum[(size_t)(N0 + n)*MT + mt_blk] = redbuf[i0]   + redbuf[i1];
    psq [(size_t)(N0 + n)*MT + mt_blk] = redbuf[i0+1] + redbuf[i1+1];
  }
}

// ---------------- conv3x3 implicit GEMM, swizzled LDS + dbuf single-barrier ----------------
// K=32/barrier, 2x4096 buffers (34KB LDS, VGPR~116): R5's K=64 variant spilled
// (WRITE_SIZE 34->404MB, MfmaUtil 28->11) -- do NOT widen the pipeline again.
__global__ __launch_bounds__(256) void k_conv3(const u16* __restrict__ xm, const u16* __restrict__ w1t,
    u16* __restrict__ y, float* __restrict__ psum, float* __restrict__ psq, const u16* __restrict__ zp){
  __shared__ __attribute__((aligned(16))) u16 As[2*4096];
  __shared__ __attribute__((aligned(16))) u16 Bs[2*4096];
  __shared__ __attribute__((aligned(16))) float redbuf[512];
  int bx = blockIdx.x;
  int mt_blk = ((bx >> 4) << 3) | (bx & 7);
  int nt_blk = (bx >> 3) & 1;
  int tid = threadIdx.x;
  int lane = tid & 63, wave = tid >> 6;
  int wm = wave & 1, wn = wave >> 1;
  int l15 = lane & 15, quad = lane >> 4;
  int P0 = mt_blk*128, N0 = nt_blk*128;
  int prow = tid >> 2, cg = tid & 3;
  int swzw = (cg ^ (prow & 3) ^ ((prow >> 2) & 3)) * 8;
  int wr0 = prow*32 + swzw;
  int wr1 = (prow+64)*32 + swzw;
  int rdsw = (quad ^ (l15 & 3) ^ ((l15 >> 2) & 3)) * 8;
  int rA[4], rB[4];
  #pragma unroll
  for (int i=0;i<4;i++){
    rA[i] = (wm*64 + i*16 + l15)*32 + rdsw;
    rB[i] = (wn*64 + i*16 + l15)*32 + rdsw;
  }
  const u16* b0base = w1t + (size_t)(N0 + prow)*2304 + cg*8;
  const u16* b1base = w1t + (size_t)(N0 + prow + 64)*2304 + cg*8;
  int P_0 = P0 + prow, P_1 = P0 + prow + 64;
  int h_0 = (P_0 >> 6) & 63, w_0 = P_0 & 63, bi0 = P_0 >> 12;
  int h_1 = (P_1 >> 6) & 63, w_1 = P_1 & 63, bi1 = P_1 >> 12;

  f32x4 acc[4][4];
  f32x4 zz = {0.f,0.f,0.f,0.f};
  #pragma unroll
  for (int i=0;i<4;i++)
    #pragma unroll
    for (int j=0;j<4;j++) acc[i][j] = zz;

  auto aptr0 = [&](int t)->const u16*{
    int dh = t/3 - 1, dw = t%3 - 1;
    int h2 = h_0 + dh, w2 = w_0 + dw;
    return (((unsigned)h2 < 64u) && ((unsigned)w2 < 64u))
        ? xm + (((size_t)bi0*HW + h2*64 + w2)*CH) + cg*8 : zp + cg*8;
  };
  auto aptr1 = [&](int t)->const u16*{
    int dh = t/3 - 1, dw = t%3 - 1;
    int h2 = h_1 + dh, w2 = w_1 + dw;
    return (((unsigned)h2 < 64u) && ((unsigned)w2 < 64u))
        ? xm + (((size_t)bi1*HW + h2*64 + w2)*CH) + cg*8 : zp + cg*8;
  };

  const u16 *pa0 = aptr0(0), *pa1 = aptr1(0);
  const u16 *pb0 = b0base,   *pb1 = b1base;
  uint4 ra0 = *(const uint4*)pa0;
  uint4 ra1 = *(const uint4*)pa1;
  uint4 rb0 = *(const uint4*)pb0;
  uint4 rb1 = *(const uint4*)pb1;

  for (int t=0; t<9; t++){
    #pragma unroll
    for (int ci=0; ci<8; ci++){
      const int bo = (ci & 1) * 4096;   // buf parity: (t*8+ci)%2 == ci%2
      *(uint4*)&As[bo + wr0] = ra0;
      *(uint4*)&As[bo + wr1] = ra1;
      *(uint4*)&Bs[bo + wr0] = rb0;
      *(uint4*)&Bs[bo + wr1] = rb1;
      __syncthreads();
      if (ci < 7){
        int off = (ci+1)*32;
        ra0 = *(const uint4*)(pa0 + off);
        ra1 = *(const uint4*)(pa1 + off);
        rb0 = *(const uint4*)(pb0 + off);
        rb1 = *(const uint4*)(pb1 + off);
      } else if (t < 8){
        pa0 = aptr0(t+1); pa1 = aptr1(t+1);
        pb0 = b0base + (t+1)*256; pb1 = b1base + (t+1)*256;
        ra0 = *(const uint4*)pa0;
        ra1 = *(const uint4*)pa1;
        rb0 = *(const uint4*)pb0;
        rb1 = *(const uint4*)pb1;
      }
      bf16x8 af[4], bv[4];
      #pragma unroll
      for (int i=0;i<4;i++) af[i] = *(const bf16x8*)&As[bo + rA[i]];
      #pragma unroll
      for (int i=0;i<4;i++) bv[i] = *(const bf16x8*)&Bs[bo + rB[i]];
      #pragma unroll
      for (int i=0;i<4;i++)
        #pragma unroll
        for (int j=0;j<4;j++)
          acc[i][j] = __builtin_amdgcn_mfma_f32_16x16x32_bf16(af[i], bv[j], acc[i][j], 0, 0, 0);
    }
  }
  epilogue_store(acc, P0, N0, wm, wn, l15, quad, tid, mt_blk, y, psum, psq, redbuf);
}

// ---------------- 1x1 conv GEMM (sc and conv2), K=32/barrier dbuf ----------------
__global__ __launch_bounds__(256) void k_gemm1x1(const u16* __restrict__ A, const u16* __restrict__ Bw,
    u16* __restrict__ y, float* __restrict__ psum, float* __restrict__ psq){
  __shared__ __attribute__((aligned(16))) u16 As[2*4096];
  __shared__ __attribute__((aligned(16))) u16 Bs[2*4096];
  __shared__ __attribute__((aligned(16))) float redbuf[512];
  int bx = blockIdx.x;
  int mt_blk = ((bx >> 4) << 3) | (bx & 7);
  int nt_blk = (bx >> 3) & 1;
  int tid = threadIdx.x;
  int lane = tid & 63, wave = tid >> 6;
  int wm = wave & 1, wn = wave >> 1;
  int l15 = lane & 15, quad = lane >> 4;
  int P0 = mt_blk*128, N0 = nt_blk*128;
  int prow = tid >> 2, cg = tid & 3;
  int swzw = (cg ^ (prow & 3) ^ ((prow >> 2) & 3)) * 8;
  int wr0 = prow*32 + swzw;
  int wr1 = (prow+64)*32 + swzw;
  int rdsw = (quad ^ (l15 & 3) ^ ((l15 >> 2) & 3)) * 8;
  int rA[4], rB[4];
  #pragma unroll
  for (int i=0;i<4;i++){
    rA[i] = (wm*64 + i*16 + l15)*32 + rdsw;
    rB[i] = (wn*64 + i*16 + l15)*32 + rdsw;
  }
  const u16* a0p = A  + ((size_t)(P0 + prow))*CH + cg*8;
  const u16* a1p = A  + ((size_t)(P0 + prow + 64))*CH + cg*8;
  const u16* b0p = Bw + ((size_t)(N0 + prow))*CH + cg*8;
  const u16* b1p = Bw + ((size_t)(N0 + prow + 64))*CH + cg*8;
  f32x4 acc[4][4];
  f32x4 zz = {0.f,0.f,0.f,0.f};
  #pragma unroll
  for (int i=0;i<4;i++)
    #pragma unroll
    for (int j=0;j<4;j++) acc[i][j] = zz;

  uint4 ra0 = *(const uint4*)a0p;
  uint4 ra1 = *(const uint4*)a1p;
  uint4 rb0 = *(const uint4*)b0p;
  uint4 rb1 = *(const uint4*)b1p;

  #pragma unroll
  for (int ci=0; ci<8; ci++){
    const int bo = (ci & 1) * 4096;
    *(uint4*)&As[bo + wr0] = ra0;
    *(uint4*)&As[bo + wr1] = ra1;
    *(uint4*)&Bs[bo + wr0] = rb0;
    *(uint4*)&Bs[bo + wr1] = rb1;
    __syncthreads();
    if (ci < 7){
      int off = (ci+1)*32;
      ra0 = *(const uint4*)(a0p + off);
      ra1 = *(const uint4*)(a1p + off);
      rb0 = *(const uint4*)(b0p + off);
      rb1 = *(const uint4*)(b1p + off);
    }
    bf16x8 af[4], bv[4];
    #pragma unroll
    for (int i=0;i<4;i++) af[i] = *(const bf16x8*)&As[bo + rA[i]];
    #pragma unroll
    for (int i=0;i<4;i++) bv[i] = *(const bf16x8*)&Bs[bo + rB[i]];
    #pragma unroll
    for (int i=0;i<4;i++)
      #pragma unroll
      for (int j=0;j<4;j++)
        acc[i][j] = __builtin_amdgcn_mfma_f32_16x16x32_bf16(af[i], bv[j], acc[i][j], 0, 0, 0);
  }
  epilogue_store(acc, P0, N0, wm, wn, l15, quad, tid, mt_blk, y, psum, psq, redbuf);
}

// ---------------- BN stat finalize: one block per channel, coalesced ----------------
__global__ __launch_bounds__(64) void k_bnstat(const float* __restrict__ psum, const float* __restrict__ psq,
    const float* __restrict__ g, const float* __restrict__ be,
    float* __restrict__ scale, float* __restrict__ shift){
  int c = blockIdx.x, t = threadIdx.x;
  const float* ps = psum + (size_t)c*MT;
  const float* pq = psq  + (size_t)c*MT;
  float s=0.f, q=0.f;
  #pragma unroll
  for (int i=0;i<8;i++){ s += ps[t + i*64]; q += pq[t + i*64]; }
  #pragma unroll
  for (int off=32; off>0; off>>=1){
    s += __shfl_down(s, off);
    q += __shfl_down(q, off);
  }
  if (t == 0){
    float mean = s * (1.f/65536.f);
    float var  = q * (1.f/65536.f) - mean*mean;
    float rstd = rsqrtf(var + 1e-5f);
    float sc = g[c]*rstd;
    scale[c] = sc;
    shift[c] = be[c] - mean*sc;
  }
}

// ---------------- bb1 = silu(bn1(y1)) elementwise on NHWC bf16 ----------------
__global__ __launch_bounds__(256) void k_bb(const u16* __restrict__ y1, const float* __restrict__ sc1,
    const float* __restrict__ sh1, u16* __restrict__ bb){
  __shared__ float sc[256], sh[256];
  int tid = threadIdx.x;
  sc[tid] = sc1[tid]; sh[tid] = sh1[tid];
  __syncthreads();
  size_t i = ((size_t)blockIdx.x*256 + tid)*8;
  int c0 = (int)(i & 255);
  uint4 v = *(const uint4*)(y1 + i);
  u32 a[4] = {v.x, v.y, v.z, v.w};
  u32 o[4];
  #pragma unroll
  for (int p=0;p<4;p++){
    float zl = sc[c0+2*p]*bflo(a[p]) + sh[c0+2*p];
    float zh = sc[c0+2*p+1]*bfhi(a[p]) + sh[c0+2*p+1];
    float ol = zl/(1.f+__expf(-zl));
    float oh = zh/(1.f+__expf(-zh));
    o[p] = (u32)f2bf(ol) | ((u32)f2bf(oh) << 16);
  }
  uint4 w; w.x=o[0]; w.y=o[1]; w.z=o[2]; w.w=o[3];
  *(uint4*)(bb + i) = w;
}

// ---------------- out = silu(bn2(y2)+bns(ysc)), NHWC bf16 -> NCHW f32 ----------------
__global__ __launch_bounds__(256) void k_final(const u16* __restrict__ y2, const u16* __restrict__ ysc,
    const float* __restrict__ sc2, const float* __restrict__ sh2,
    const float* __restrict__ scs, const float* __restrict__ shs,
    float* __restrict__ out){
  __shared__ __attribute__((aligned(16))) float tile[64*257];
  __shared__ float l2s[64], l2h[64], lss[64], lsh[64];
  int pt = blockIdx.x, ct = blockIdx.y, tid = threadIdx.x;
  int C0 = ct << 6;
  if (tid < 64){ l2s[tid]=sc2[C0+tid]; l2h[tid]=sh2[C0+tid]; lss[tid]=scs[C0+tid]; lsh[tid]=shs[C0+tid]; }
  __syncthreads();
  size_t P0 = (size_t)pt * 256;
  int b = pt >> 4; int rem = (pt & 15) << 8;
  {
    int g = tid & 7, p0 = tid >> 3;
    for (int k=0;k<8;k++){
      int pos = p0 + k*32;
      size_t off = (P0+pos)*CH + C0 + g*8;
      uint4 va = *(const uint4*)(y2 + off);
      uint4 vb = *(const uint4*)(ysc + off);
      u32 aa[4] = {va.x,va.y,va.z,va.w};
      u32 bv[4] = {vb.x,vb.y,vb.z,vb.w};
      #pragma unroll
      for (int p=0;p<4;p++){
        int c = g*8 + 2*p;
        float z0 = l2s[c]*bflo(aa[p]) + l2h[c] + lss[c]*bflo(bv[p]) + lsh[c];
        float z1 = l2s[c+1]*bfhi(aa[p]) + l2h[c+1] + lss[c+1]*bfhi(bv[p]) + lsh[c+1];
        tile[c*257 + pos]     = z0/(1.f+__expf(-z0));
        tile[(c+1)*257 + pos] = z1/(1.f+__expf(-z1));
      }
    }
  }
  __syncthreads();
  {
    int c = tid >> 2, q = tid & 3;
    float* op = out + ((size_t)(b*256 + C0 + c))*HW + rem;
    #pragma unroll
    for (int k=0;k<16;k++){
      int pos = q*64 + k*4;
      float4 v;
      v.x = tile[c*257 + pos];
      v.y = tile[c*257 + pos + 1];
      v.z = tile[c*257 + pos + 2];
      v.w = tile[c*257 + pos + 3];
      *(float4*)(op + pos) = v;
    }
  }
}

extern "C" void kernel_launch(void* const* d_in, const int* in_sizes, int n_in,
                              void* d_out, int out_size, void* d_ws, size_t ws_size,
                              hipStream_t stream){
  const float* x     = (const float*)d_in[0];
  const float* dce   = (const float*)d_in[1];
  const float* w_dce = (const float*)d_in[2];
  const float* b_dce = (const float*)d_in[3];
  const float* w_ch  = (const float*)d_in[4];
  const float* w_sh  = (const float*)d_in[5];
  const float* b_sh  = (const float*)d_in[6];
  const float* w_ex  = (const float*)d_in[7];
  const float* b_ex  = (const float*)d_in[8];
  const float* w_c1  = (const float*)d_in[9];
  const float* g1    = (const float*)d_in[10];
  const float* be1   = (const float*)d_in[11];
  const float* w_c2  = (const float*)d_in[12];
  const float* g2    = (const float*)d_in[13];
  const float* be2   = (const float*)d_in[14];
  const float* w_s   = (const float*)d_in[15];
  const float* gs    = (const float*)d_in[16];
  const float* bes   = (const float*)d_in[17];
  float* out = (float*)d_out;
  char* ws = (char*)d_ws;

  const size_t NB = (size_t)NPOS*CH*2;   // 32 MiB per bf16 tensor
  u16* xm  = (u16*)(ws);
  u16* y1  = (u16*)(ws + NB);
  u16* ysc = (u16*)(ws + 2*NB);
  u16* bb  = (u16*)(ws + 3*NB);
  char* p = ws + 4*NB;
  u16* w1t   = (u16*)p; p += (size_t)256*2304*2;
  u16* wsct  = (u16*)p; p += (size_t)256*256*2;
  u16* w2t   = (u16*)p; p += (size_t)256*256*2;
  float* statsx = (float*)p; p += (size_t)16*256*9*4;
  float* modb   = (float*)p; p += (size_t)16*256*4;
  float* p1s = (float*)p; p += (size_t)MT*256*4;
  float* p1q = (float*)p; p += (size_t)MT*256*4;
  float* pss = (float*)p; p += (size_t)MT*256*4;
  float* psqv= (float*)p; p += (size_t)MT*256*4;
  float* p2s = (float*)p; p += (size_t)MT*256*4;
  float* p2q = (float*)p; p += (size_t)MT*256*4;
  float* bn1sc = (float*)p; p += 1024;
  float* bn1sh = (float*)p; p += 1024;
  float* bnssc = (float*)p; p += 1024;
  float* bnssh = (float*)p; p += 1024;
  float* bn2sc = (float*)p; p += 1024;
  float* bn2sh = (float*)p; p += 1024;
  u16* zp = (u16*)p; p += 4096;

  hipMemsetAsync(zp, 0, 4096, stream);
  k_statsx<<<4096, 256, 0, stream>>>(x, statsx);
  k_wprep<<<2816, 256, 0, stream>>>(w_c1, w_s, w_c2, w1t, wsct, w2t);
  k_gate<<<16, 256, 0, stream>>>(dce, statsx, w_ch, w_dce, b_dce, w_sh, b_sh, w_ex, b_ex, modb);
  k_xm<<<dim3(256,4), 256, 0, stream>>>(x, modb, xm);
  k_conv3<<<1024, 256, 0, stream>>>(xm, w1t, y1, p1s, p1q, zp);
  k_bnstat<<<256, 64, 0, stream>>>(p1s, p1q, g1, be1, bn1sc, bn1sh);
  k_bb<<<8192, 256, 0, stream>>>(y1, bn1sc, bn1sh, bb);
  k_gemm1x1<<<1024, 256, 0, stream>>>(xm, wsct, ysc, pss, psqv);
  k_bnstat<<<256, 64, 0, stream>>>(pss, psqv, gs, bes, bnssc, bnssh);
  k_gemm1x1<<<1024, 256, 0, stream>>>(bb, w2t, y1 /*=y2*/, p2s, p2q);
  k_bnstat<<<256, 64, 0, stream>>>(p2s, p2q, g2, be2, bn2sc, bn2sh);
  k_final<<<dim3(256,4), 256, 0, stream>>>(y1, ysc, bn2sc, bn2sh, bnssc, bnssh, out);
}